// Round 1
// baseline (1191.445 us; speedup 1.0000x reference)
//
#include <hip/hip_runtime.h>
#include <hip/hip_bf16.h>

#define DEVI static __device__ __forceinline__

typedef __attribute__((ext_vector_type(4))) float f32x4;
typedef __attribute__((ext_vector_type(8))) __bf16 bf16x8;
typedef __attribute__((ext_vector_type(8))) unsigned short u16x8;
typedef __attribute__((ext_vector_type(4))) unsigned short u16x4;

DEVI unsigned short f2b(float f) {
  union { float f; unsigned u; } v; v.f = f;
  unsigned r = v.u + 0x7fffu + ((v.u >> 16) & 1u);
  return (unsigned short)(r >> 16);
}
DEVI float b2f(unsigned short b) {
  union { unsigned u; float f; } v; v.u = ((unsigned)b) << 16; return v.f;
}
DEVI bf16x8 ldb8(const unsigned short* p) {
  return __builtin_bit_cast(bf16x8, *(const u16x8*)p);
}
#define MFMA16(a, b, c) __builtin_amdgcn_mfma_f32_16x16x32_bf16(a, b, c, 0, 0, 0)

// ---------------------------------------------------------------------------
// Transpose fp32 weight [K=1024][N=1024] -> bf16 Wt[N][K]
__global__ __launch_bounds__(256) void transpose_w(const float* __restrict__ w,
                                                   unsigned short* __restrict__ wt) {
  __shared__ float t[64][65];
  int k0 = blockIdx.y * 64, n0 = blockIdx.x * 64;
  int tid = threadIdx.x;
  int r = tid / 16, c = tid % 16;
  #pragma unroll
  for (int p = 0; p < 4; ++p) {
    int kr = p * 16 + r;
    float4 v = *(const float4*)&w[(size_t)(k0 + kr) * 1024 + n0 + c * 4];
    t[kr][c * 4 + 0] = v.x; t[kr][c * 4 + 1] = v.y;
    t[kr][c * 4 + 2] = v.z; t[kr][c * 4 + 3] = v.w;
  }
  __syncthreads();
  #pragma unroll
  for (int p = 0; p < 4; ++p) {
    int nr = p * 16 + r;
    u16x4 o = { f2b(t[c * 4 + 0][nr]), f2b(t[c * 4 + 1][nr]),
                f2b(t[c * 4 + 2][nr]), f2b(t[c * 4 + 3][nr]) };
    *(u16x4*)&wt[(size_t)(n0 + nr) * 1024 + k0 + c * 4] = o;
  }
}

// ---------------------------------------------------------------------------
// Transpose bf16 V [bh][2048][64] -> Vt [bh][64][2048]
__global__ __launch_bounds__(256) void transpose_v(const unsigned short* __restrict__ v,
                                                   unsigned short* __restrict__ vt) {
  __shared__ unsigned short t[64][72];
  int bh = blockIdx.y;
  int s0 = blockIdx.x * 64;
  int tid = threadIdx.x;
  int r = tid / 8, g = tid % 8;
  #pragma unroll
  for (int p = 0; p < 2; ++p) {
    int sr = p * 32 + r;
    *(u16x8*)&t[sr][g * 8] = *(const u16x8*)&v[((size_t)bh * 2048 + s0 + sr) * 64 + g * 8];
  }
  __syncthreads();
  #pragma unroll
  for (int p = 0; p < 2; ++p) {
    int dr = p * 32 + r;
    u16x8 o;
    #pragma unroll
    for (int e = 0; e < 8; ++e) o[e] = t[g * 8 + e][dr];
    *(u16x8*)&vt[((size_t)bh * 64 + dr) * 2048 + s0 + g * 8] = o;
  }
}

// ---------------------------------------------------------------------------
// GEMM: Y[M,N] = X[M,K] @ Wt[N,K]^T + bias.  128x128 tile, BK=32, 4 waves.
// OUTMODE 0: store bf16 permuted to [B=2][H=16][S=2048][64] (n = h*64+d, m = b*2048+s)
// OUTMODE 1: store fp32 row-major [M][N]
template<int OUTMODE, typename TX>
__global__ __launch_bounds__(256) void gemm_bf16(
    const TX* __restrict__ X, const unsigned short* __restrict__ Wt,
    const float* __restrict__ bias, void* __restrict__ outv,
    int M, int N, int K) {
  __shared__ unsigned short a_lds[128][40];
  __shared__ unsigned short b_lds[128][40];
  int tid = threadIdx.x;
  int m0 = blockIdx.y * 128, n0 = blockIdx.x * 128;
  int wave = tid >> 6, lane = tid & 63, lg = lane >> 4, lr = lane & 15;
  int wr = wave >> 1, wc = wave & 1;
  const f32x4 z = {0.f, 0.f, 0.f, 0.f};
  f32x4 acc[4][4];
  #pragma unroll
  for (int r = 0; r < 4; ++r)
    #pragma unroll
    for (int c = 0; c < 4; ++c) acc[r][c] = z;

  int ra = tid >> 3, cg = tid & 7;  // A staging
  int rb = tid >> 2, kg = tid & 3;  // B staging

  for (int k0 = 0; k0 < K; k0 += 32) {
    #pragma unroll
    for (int p = 0; p < 4; ++p) {
      int row = p * 32 + ra;
      if constexpr (sizeof(TX) == 4) {
        float4 v = *(const float4*)&X[(size_t)(m0 + row) * K + k0 + cg * 4];
        u16x4 o = { f2b(v.x), f2b(v.y), f2b(v.z), f2b(v.w) };
        *(u16x4*)&a_lds[row][cg * 4] = o;
      } else {
        *(u16x4*)&a_lds[row][cg * 4] =
            *(const u16x4*)&X[(size_t)(m0 + row) * K + k0 + cg * 4];
      }
    }
    #pragma unroll
    for (int p = 0; p < 2; ++p) {
      int row = p * 64 + rb;
      *(u16x8*)&b_lds[row][kg * 8] =
          *(const u16x8*)&Wt[(size_t)(n0 + row) * K + k0 + kg * 8];
    }
    __syncthreads();
    bf16x8 af[4], bfr[4];
    #pragma unroll
    for (int r = 0; r < 4; ++r) af[r] = ldb8(&a_lds[wr * 64 + r * 16 + lr][lg * 8]);
    #pragma unroll
    for (int c = 0; c < 4; ++c) bfr[c] = ldb8(&b_lds[wc * 64 + c * 16 + lr][lg * 8]);
    #pragma unroll
    for (int r = 0; r < 4; ++r)
      #pragma unroll
      for (int c = 0; c < 4; ++c)
        acc[r][c] = MFMA16(af[r], bfr[c], acc[r][c]);
    __syncthreads();
  }

  #pragma unroll
  for (int r = 0; r < 4; ++r) {
    #pragma unroll
    for (int c = 0; c < 4; ++c) {
      #pragma unroll
      for (int j = 0; j < 4; ++j) {
        int m = m0 + wr * 64 + r * 16 + lg * 4 + j;
        int n = n0 + wc * 64 + c * 16 + lr;
        float val = acc[r][c][j] + bias[n];
        if constexpr (OUTMODE == 0) {
          int bb = m >> 11, s = m & 2047, hh = n >> 6, d = n & 63;
          ((unsigned short*)outv)[(((size_t)(bb * 16 + hh) * 2048 + s) << 6) + d] = f2b(val);
        } else {
          ((float*)outv)[(size_t)m * N + n] = val;
        }
      }
    }
  }
}

// ---------------------------------------------------------------------------
// Fused attention: per block = one (b,h) and 64 q-rows; 4 waves x 16 rows.
// Pass 1: l = sum_k exp(s) (no max subtraction: |s| <= ~15, fp32-safe).
// Pass 2: recompute s, attn = exp(s)/l -> fp32 global (coalesced via p_lds),
//         PV accumulate with bf16 fragments.  K/V read direct from global (L2-resident).
__global__ __launch_bounds__(256) void attn_fused(
    const unsigned short* __restrict__ qh,   // [bh][2048][64] bf16
    const unsigned short* __restrict__ kh,   // [bh][2048][64] bf16
    const unsigned short* __restrict__ vt,   // [bh][64][2048] bf16
    const unsigned char* __restrict__ mask,  // [B][2048][2048] bool
    float* __restrict__ attn_out,            // [H*B][2048][2048] fp32
    unsigned short* __restrict__ ctx) {      // [B*2048][1024] bf16
  __shared__ float p_lds[4][16][68];
  int bid = blockIdx.x;
  int qb = bid & 31, bh = bid >> 5;
  int b = bh >> 4, h = bh & 15;
  int tid = threadIdx.x, wave = tid >> 6, lane = tid & 63, lg = lane >> 4, lr = lane & 15;
  int qbase = qb * 64 + wave * 16;
  const f32x4 z = {0.f, 0.f, 0.f, 0.f};

  const unsigned short* qrow = &qh[((size_t)bh * 2048 + qbase + lr) * 64];
  bf16x8 aq0 = ldb8(&qrow[lg * 8]);
  bf16x8 aq1 = ldb8(&qrow[32 + lg * 8]);
  const unsigned short* kbase = &kh[(size_t)bh * 2048 * 64];
  const unsigned short* vbase = &vt[(size_t)bh * 64 * 2048];
  const unsigned char* mbase = &mask[((size_t)b * 2048 + qbase) * 2048];

  // ---- pass 1: denominators
  float lacc[4] = {0.f, 0.f, 0.f, 0.f};
  for (int kt = 0; kt < 2048; kt += 64) {
    #pragma unroll
    for (int t = 0; t < 4; ++t) {
      const unsigned short* krow = &kbase[(size_t)(kt + t * 16 + lr) * 64];
      f32x4 c = z;
      c = MFMA16(aq0, ldb8(&krow[lg * 8]), c);
      c = MFMA16(aq1, ldb8(&krow[32 + lg * 8]), c);
      #pragma unroll
      for (int j = 0; j < 4; ++j) {
        float sc = c[j] * 0.125f;
        if (mbase[(size_t)(lg * 4 + j) * 2048 + kt + t * 16 + lr]) sc = -1e30f;
        lacc[j] += __expf(sc);
      }
    }
  }
  float inv_l[4];
  #pragma unroll
  for (int j = 0; j < 4; ++j) {
    float s = lacc[j];
    #pragma unroll
    for (int off = 1; off < 16; off <<= 1) s += __shfl_xor(s, off);
    inv_l[j] = 1.0f / s;
  }

  // ---- pass 2: write attn + PV
  f32x4 accv[4];
  #pragma unroll
  for (int t = 0; t < 4; ++t) accv[t] = z;
  float* arow = &attn_out[(((size_t)(h * 2 + b) * 2048) + qbase) * 2048];

  for (int kt = 0; kt < 2048; kt += 64) {
    #pragma unroll
    for (int t = 0; t < 4; ++t) {
      const unsigned short* krow = &kbase[(size_t)(kt + t * 16 + lr) * 64];
      f32x4 c = z;
      c = MFMA16(aq0, ldb8(&krow[lg * 8]), c);
      c = MFMA16(aq1, ldb8(&krow[32 + lg * 8]), c);
      #pragma unroll
      for (int j = 0; j < 4; ++j) {
        float sc = c[j] * 0.125f;
        if (mbase[(size_t)(lg * 4 + j) * 2048 + kt + t * 16 + lr]) sc = -1e30f;
        p_lds[wave][lg * 4 + j][t * 16 + lr] = __expf(sc) * inv_l[j];
      }
    }
    // coalesced fp32 attn store (wave-local LDS, in-order DS => no barrier)
    #pragma unroll
    for (int r16 = 0; r16 < 16; ++r16)
      arow[(size_t)r16 * 2048 + kt + lane] = p_lds[wave][r16][lane];
    // PV: A-fragments from p_lds (convert to bf16 in regs)
    f32x4 pa0a = *(const f32x4*)&p_lds[wave][lr][lg * 8];
    f32x4 pa0b = *(const f32x4*)&p_lds[wave][lr][lg * 8 + 4];
    f32x4 pa1a = *(const f32x4*)&p_lds[wave][lr][32 + lg * 8];
    f32x4 pa1b = *(const f32x4*)&p_lds[wave][lr][32 + lg * 8 + 4];
    u16x8 u0, u1;
    #pragma unroll
    for (int j = 0; j < 4; ++j) {
      u0[j] = f2b(pa0a[j]); u0[4 + j] = f2b(pa0b[j]);
      u1[j] = f2b(pa1a[j]); u1[4 + j] = f2b(pa1b[j]);
    }
    bf16x8 pa0 = __builtin_bit_cast(bf16x8, u0);
    bf16x8 pa1 = __builtin_bit_cast(bf16x8, u1);
    #pragma unroll
    for (int t = 0; t < 4; ++t) {
      const unsigned short* vrow = &vbase[(size_t)(t * 16 + lr) * 2048 + kt];
      accv[t] = MFMA16(pa0, ldb8(&vrow[lg * 8]), accv[t]);
      accv[t] = MFMA16(pa1, ldb8(&vrow[32 + lg * 8]), accv[t]);
    }
  }
  #pragma unroll
  for (int t = 0; t < 4; ++t)
    #pragma unroll
    for (int j = 0; j < 4; ++j)
      ctx[((size_t)b * 2048 + qbase + lg * 4 + j) * 1024 + h * 64 + t * 16 + lr] =
          f2b(accv[t][j]);
}

// ---------------------------------------------------------------------------
// Residual + LayerNorm: one block per row of 1024
__global__ __launch_bounds__(256) void ln_kernel(
    const float* __restrict__ fc, const float* __restrict__ xq,
    const float* __restrict__ gamma, const float* __restrict__ beta,
    float* __restrict__ out) {
  __shared__ float red[8];
  int row = blockIdx.x, tid = threadIdx.x;
  size_t base = (size_t)row * 1024 + tid * 4;
  float4 v = *(const float4*)&fc[base];
  float4 x = *(const float4*)&xq[base];
  float a0 = v.x + x.x, a1 = v.y + x.y, a2 = v.z + x.z, a3 = v.w + x.w;
  float s1 = a0 + a1 + a2 + a3;
  float s2 = a0 * a0 + a1 * a1 + a2 * a2 + a3 * a3;
  #pragma unroll
  for (int off = 1; off < 64; off <<= 1) {
    s1 += __shfl_xor(s1, off);
    s2 += __shfl_xor(s2, off);
  }
  int wave = tid >> 6;
  if ((tid & 63) == 0) { red[wave] = s1; red[4 + wave] = s2; }
  __syncthreads();
  s1 = red[0] + red[1] + red[2] + red[3];
  s2 = red[4] + red[5] + red[6] + red[7];
  float mu = s1 * (1.f / 1024.f);
  float var = s2 * (1.f / 1024.f) - mu * mu;
  float rs = rsqrtf(var + 1e-5f);
  float4 g = *(const float4*)&gamma[tid * 4];
  float4 be = *(const float4*)&beta[tid * 4];
  float4 o;
  o.x = (a0 - mu) * rs * g.x + be.x;
  o.y = (a1 - mu) * rs * g.y + be.y;
  o.z = (a2 - mu) * rs * g.z + be.z;
  o.w = (a3 - mu) * rs * g.w + be.w;
  *(float4*)&out[base] = o;
}

// ---------------------------------------------------------------------------
extern "C" void kernel_launch(void* const* d_in, const int* in_sizes, int n_in,
                              void* d_out, int out_size, void* d_ws, size_t ws_size,
                              hipStream_t stream) {
  const float* input_q = (const float*)d_in[0];
  const float* input_k = (const float*)d_in[1];
  const float* input_v = (const float*)d_in[2];
  const unsigned char* mask = (const unsigned char*)d_in[3];
  const float* w_q = (const float*)d_in[4];
  const float* b_q = (const float*)d_in[5];
  const float* w_k = (const float*)d_in[6];
  const float* b_k = (const float*)d_in[7];
  const float* w_v = (const float*)d_in[8];
  const float* b_v = (const float*)d_in[9];
  const float* w_fc = (const float*)d_in[10];
  const float* b_fc = (const float*)d_in[11];
  const float* gamma = (const float*)d_in[12];
  const float* beta = (const float*)d_in[13];

  char* ws = (char*)d_ws;
  unsigned short* qh  = (unsigned short*)(ws);                      // 8 MB
  unsigned short* kh  = (unsigned short*)(ws + ((size_t)8 << 20));  // 8 MB
  unsigned short* vh  = (unsigned short*)(ws + ((size_t)16 << 20)); // 8 MB
  unsigned short* vt  = (unsigned short*)(ws + ((size_t)24 << 20)); // 8 MB
  unsigned short* ctx = (unsigned short*)(ws + ((size_t)32 << 20)); // 8 MB
  unsigned short* wtq = (unsigned short*)(ws + ((size_t)40 << 20)); // 4 x 2 MB
  unsigned short* wtk = wtq + (1u << 20);
  unsigned short* wtv = wtk + (1u << 20);
  unsigned short* wtf = wtv + (1u << 20);
  float* fc_out = (float*)(ws);  // 16 MB, reuses qh+kh (dead by then)

  float* out = (float*)d_out;
  float* attn_out = out + (size_t)2 * 2048 * 1024;

  transpose_w<<<dim3(16, 16), 256, 0, stream>>>(w_q, wtq);
  transpose_w<<<dim3(16, 16), 256, 0, stream>>>(w_k, wtk);
  transpose_w<<<dim3(16, 16), 256, 0, stream>>>(w_v, wtv);
  transpose_w<<<dim3(16, 16), 256, 0, stream>>>(w_fc, wtf);

  gemm_bf16<0, float><<<dim3(8, 32), 256, 0, stream>>>(input_q, wtq, b_q, qh, 4096, 1024, 1024);
  gemm_bf16<0, float><<<dim3(8, 32), 256, 0, stream>>>(input_k, wtk, b_k, kh, 4096, 1024, 1024);
  gemm_bf16<0, float><<<dim3(8, 32), 256, 0, stream>>>(input_v, wtv, b_v, vh, 4096, 1024, 1024);

  transpose_v<<<dim3(32, 32), 256, 0, stream>>>(vh, vt);

  attn_fused<<<dim3(1024), 256, 0, stream>>>(qh, kh, vt, mask, attn_out, ctx);

  gemm_bf16<1, unsigned short><<<dim3(8, 32), 256, 0, stream>>>(ctx, wtf, b_fc, fc_out, 4096, 1024, 1024);

  ln_kernel<<<dim3(4096), 256, 0, stream>>>(fc_out, input_q, gamma, beta, out);
}